// Round 3
// baseline (300.478 us; speedup 1.0000x reference)
//
#include <hip/hip_runtime.h>
#include <stdint.h>

// Problem constants
#define B_     16
#define N_     512
#define R_     10
#define DE_    256
#define DR_    64
#define DOUT_  256
#define INDIM_ 3200   // (DE+DR)*R
#define BLK_   320    // DE+DR
#define RN_    5120   // R*N, K-extent of stage B
#define SPLITS_ 4     // stage B split-K factor
#define CPS_    20    // BK=64 chunks per split (80 total / 4)

typedef __bf16          v8bf  __attribute__((ext_vector_type(8)));
typedef unsigned short  v8us  __attribute__((ext_vector_type(8)));
typedef unsigned short  v4us  __attribute__((ext_vector_type(4)));
typedef float           f32x4 __attribute__((ext_vector_type(4)));

static __device__ __forceinline__ unsigned short f2b(float f) {
  union { float f; unsigned u; } c; c.f = f;
  unsigned r = c.u + 0x7FFFu + ((c.u >> 16) & 1u);   // RNE
  return (unsigned short)(r >> 16);
}

static __device__ __forceinline__ v8bf us2bf(v8us u) {
  union { v8us u; v8bf b; } c; c.u = u; return c.b;
}

// async global->LDS, 16B per lane; LDS dest = wave-uniform base + lane*16
static __device__ __forceinline__ void gl_lds16(const void* g, void* l) {
  __builtin_amdgcn_global_load_lds(
      (const __attribute__((address_space(1))) void*)g,
      (__attribute__((address_space(3))) void*)l, 16, 0, 0);
}

static __device__ __forceinline__ void waitv12() { asm volatile("s_waitcnt vmcnt(12)" ::: "memory"); }
static __device__ __forceinline__ void waitv8()  { asm volatile("s_waitcnt vmcnt(8)"  ::: "memory"); }
static __device__ __forceinline__ void waitv0()  { asm volatile("s_waitcnt vmcnt(0)"  ::: "memory"); }
static __device__ __forceinline__ void waitl0()  { asm volatile("s_waitcnt lgkmcnt(0)" ::: "memory"); }
#define SCHED0() __builtin_amdgcn_sched_barrier(0)

// ---------------- merged prep: nodeB + WnB + Uf in one launch ------------------
__global__ void prep_all(const float* __restrict__ nf, const float* __restrict__ W,
                         const float* __restrict__ rel,
                         unsigned short* __restrict__ nodeB,
                         unsigned short* __restrict__ WnB,
                         float* __restrict__ Uf) {
  const int bb = blockIdx.x;
  const int tid = threadIdx.x;
  if (bb < 256) {
    const size_t base = (size_t)bb * 8192;
#pragma unroll
    for (int p = 0; p < 4; ++p) {
      size_t off = base + (size_t)p * 2048 + (size_t)tid * 8;
      float4 x = *(const float4*)(nf + off);
      float4 y = *(const float4*)(nf + off + 4);
      v8us u;
      u[0] = f2b(x.x); u[1] = f2b(x.y); u[2] = f2b(x.z); u[3] = f2b(x.w);
      u[4] = f2b(y.x); u[5] = f2b(y.y); u[6] = f2b(y.z); u[7] = f2b(y.w);
      *(v8us*)(nodeB + off) = u;
    }
  } else if (bb < 896) {
    int idx = (bb - 256) * 1024 + tid * 4;          // < 655360, 4-aligned
    int r = idx >> 16;
    int o = (idx >> 8) & 255;
    int d = idx & 255;                               // 4-aligned, stays in row
    float4 x = *(const float4*)(W + (size_t)o * INDIM_ + r * BLK_ + d);
    v4us u;
    u[0] = f2b(x.x); u[1] = f2b(x.y); u[2] = f2b(x.z); u[3] = f2b(x.w);
    *(v4us*)(WnB + idx) = u;
  } else {
    int idx = (bb - 896) * 256 + tid;                // < B*R*DOUT = 40960
    int o  = idx & 255;
    int br = idx >> 8;                                // b*R + r
    int r  = br % R_;
    const float* rp = rel + (size_t)br * DR_;
    const float* wp = W + (size_t)o * INDIM_ + r * BLK_ + DE_;
    float v = 0.f;
#pragma unroll 8
    for (int d = 0; d < DR_; ++d) v += rp[d] * wp[d];
    Uf[idx] = v;
  }
}

// ---------------- stage A v2: G'[b][o][(r,m)] = Wn[r] @ nodeB[b]^T + U ---------
// (unchanged from round 2)
__global__ void stageA_gemm(const unsigned short* __restrict__ nodeB,
                            const unsigned short* __restrict__ WnB,
                            const float* __restrict__ Uf,
                            unsigned short* __restrict__ Gp) {
  __shared__ unsigned short S[2 * 16384];   // 64 KB
  const int br = blockIdx.x;                // b*R + r
  const int b  = br / R_, r = br % R_;
  const int o0 = blockIdx.y * 128;
  const int m0 = blockIdx.z * 128;
  const int tid  = threadIdx.x;
  const int lane = tid & 63;
  const int wave = tid >> 6;
  const int wm = wave >> 1, wn = wave & 1;
  const int quad = lane >> 4, l16 = lane & 15;

  const unsigned short* Wb = WnB + (size_t)r * (DOUT_ * DE_);
  const unsigned short* Nb = nodeB + (size_t)b * (N_ * DE_);

  f32x4 acc[4][4];
#pragma unroll
  for (int i = 0; i < 4; ++i)
#pragma unroll
    for (int j = 0; j < 4; ++j) acc[i][j] = f32x4{0.f, 0.f, 0.f, 0.f};

  const int srl = lane >> 3;                // row within 8-row group
  const int skc = lane & 7;                 // 16B chunk within row

  // ---- prologue: stage dk=0 into buf0
  {
    unsigned short* Al = S;
    unsigned short* Bl = S + 8192;
#pragma unroll
    for (int it = 0; it < 4; ++it) {
      int rowblk = it * 32 + wave * 8;
      int rl = rowblk + srl;
      int kc = skc ^ (rl & 7);
      gl_lds16(Wb + (size_t)(o0 + rl) * DE_ + kc * 8, Al + rowblk * 64);
      gl_lds16(Nb + (size_t)(m0 + rl) * DE_ + kc * 8, Bl + rowblk * 64);
    }
  }
  __syncthreads();

  for (int t = 0; t < 4; ++t) {
    unsigned short* Sc = S + (t & 1) * 16384;
    unsigned short* Sn = S + ((t & 1) ^ 1) * 16384;
    if (t < 3) {
      const int dk = (t + 1) * 64;
      unsigned short* Aln = Sn;
      unsigned short* Bln = Sn + 8192;
#pragma unroll
      for (int it = 0; it < 4; ++it) {
        int rowblk = it * 32 + wave * 8;
        int rl = rowblk + srl;
        int kc = skc ^ (rl & 7);
        gl_lds16(Wb + (size_t)(o0 + rl) * DE_ + dk + kc * 8, Aln + rowblk * 64);
        gl_lds16(Nb + (size_t)(m0 + rl) * DE_ + dk + kc * 8, Bln + rowblk * 64);
      }
    }
    const unsigned short* Al = Sc;
    const unsigned short* Bl = Sc + 8192;
#pragma unroll
    for (int ks = 0; ks < 2; ++ks) {
      const int kb = ks * 4;
      v8bf av[4], bv[4];
#pragma unroll
      for (int mi = 0; mi < 4; ++mi) {
        int m = wm * 64 + mi * 16 + l16;
        av[mi] = us2bf(*(const v8us*)(Al + m * 64 + (((kb + quad) ^ (m & 7)) * 8)));
      }
#pragma unroll
      for (int ni = 0; ni < 4; ++ni) {
        int c = wn * 64 + ni * 16 + l16;
        bv[ni] = us2bf(*(const v8us*)(Bl + c * 64 + (((kb + quad) ^ (c & 7)) * 8)));
      }
#pragma unroll
      for (int mi = 0; mi < 4; ++mi)
#pragma unroll
        for (int ni = 0; ni < 4; ++ni)
          acc[mi][ni] = __builtin_amdgcn_mfma_f32_16x16x32_bf16(av[mi], bv[ni], acc[mi][ni], 0, 0, 0);
    }
    __syncthreads();   // drains prefetch vmcnt; next buffer ready
  }

  // epilogue: C tile -> LDS (bf16, +U) in buf0 region, then coalesced 16B stores
#pragma unroll
  for (int mi = 0; mi < 4; ++mi)
#pragma unroll
    for (int t = 0; t < 4; ++t) {
      int o_loc = wm * 64 + mi * 16 + quad * 4 + t;
      float u = Uf[(size_t)br * DOUT_ + o0 + o_loc];
#pragma unroll
      for (int ni = 0; ni < 4; ++ni) {
        int m_loc = wn * 64 + ni * 16 + l16;
        S[o_loc * 128 + m_loc] = f2b(acc[mi][ni][t] + u);
      }
    }
  __syncthreads();
#pragma unroll
  for (int p = 0; p < 8; ++p) {
    int idx16 = p * 2048 + tid * 8;         // u16 index into S
    int orow = idx16 >> 7;                  // 0..127
    int moff = idx16 & 127;
    unsigned short* dst = Gp + ((size_t)(b * DOUT_ + o0 + orow)) * RN_ + r * N_ + m0 + moff;
    *(v8us*)dst = *(const v8us*)(S + idx16);
  }
}

// ---------------- stage B v4: part[sp][b] = adj(fp32) @ G' slice ---------------
// Tile 128(n) x 256(o full DOUT), BK=64, split-K=4 (CPS=20 chunks/block).
// Grid 16x4x4 = 256 blocks (1/CU), 512 thr (8 waves 2x4, each 64n x 64o).
// Explicit software pipeline: B ring-3 (3x32KB gl_lds) + A ring-2 (2x16KB
// reg-staged), raw s_barrier + COUNTED vmcnt(12) (never 0 in main loop).
// Per iter t (post-barrier): issue B[t+2] gl_lds + A[t+3] f32 loads; MFMA on
// B[t]/A[t]; vmcnt(12) drains exactly B[t+1]+A[t+1]; convert A[t+1]->LDS;
// lgkmcnt(0). Both streams get ~2 iterations of latency budget; ring-slot
// clobbers are barrier-separated (issue post-barrier(t) vs reads pre-barrier).
// Issue order pinned with sched_barrier(0) so the vmcnt counts are exact.
__global__ __launch_bounds__(512, 1)
void stageB_gemm(const float* __restrict__ adj,
                 const unsigned short* __restrict__ Gp,
                 float* __restrict__ part) {
  __shared__ unsigned short SB[65536];      // 128 KB
  unsigned short* Bring = SB;               // 3 x 16384 u16 (32 KB each)
  unsigned short* Aring = SB + 49152;       // 2 x 8192 u16 (16 KB each)
  const int b  = blockIdx.x;
  const int n0 = blockIdx.y * 128;
  const int sp = blockIdx.z;                // chunks [sp*20, sp*20+20)
  const int tid  = threadIdx.x;
  const int lane = tid & 63;
  const int wave = tid >> 6;
  const int wm = wave >> 2;                 // 0..1 : n 64-row half
  const int wn = wave & 3;                  // 0..3 : o 64-col quarter
  const int quad = lane >> 4, l16 = lane & 15;

  const float* Ab = adj + (size_t)b * (R_ * N_ * N_);
  const unsigned short* Gb = Gp + (size_t)b * (DOUT_ * RN_);

  f32x4 acc[4][4];
#pragma unroll
  for (int i = 0; i < 4; ++i)
#pragma unroll
    for (int j = 0; j < 4; ++j) acc[i][j] = f32x4{0.f, 0.f, 0.f, 0.f};

  // A staging: thread covers rows {ar0, ar0+64}, 8 floats each at col ac8*8
  const int ar0 = tid >> 3;                 // 0..63
  const int ac8 = tid & 7;
  const int acs = ac8 ^ (ar0 & 7);          // XOR slot ((ar0+64)&7 == ar0&7)
  // B staging: per issue-round s, wave covers rows [s*64+wave*8, +8)
  const int brl = wave * 8 + (lane >> 3);
  const int bkc = lane & 7;
  const int c0 = sp * CPS_;                 // first BK=64 chunk id

  float4 As[3][4];                          // 3 in-flight A register sets

#define ISSUE_B(slot, cc) do { \
    unsigned short* Bd = Bring + (slot) * 16384; \
    const int k0b = (cc) << 6; \
    _Pragma("unroll") \
    for (int s = 0; s < 4; ++s) { \
      int rl = s * 64 + brl; \
      int kc = bkc ^ (rl & 7); \
      gl_lds16(Gb + (size_t)rl * RN_ + k0b + kc * 8, Bd + (s * 64 + wave * 8) * 64); \
    } } while (0)

#define ISSUE_A(set, cc) do { \
    const float* g = Ab + ((size_t)((cc) >> 3) * N_ + n0) * N_ + ((cc) & 7) * 64 \
                     + (size_t)ar0 * N_ + ac8 * 8; \
    As[set][0] = *(const float4*)(g); \
    As[set][1] = *(const float4*)(g + 4); \
    As[set][2] = *(const float4*)(g + 64 * N_); \
    As[set][3] = *(const float4*)(g + 64 * N_ + 4); } while (0)

#define CONV_A(set, abuf) do { \
    v8us u0, u1; \
    u0[0] = f2b(As[set][0].x); u0[1] = f2b(As[set][0].y); \
    u0[2] = f2b(As[set][0].z); u0[3] = f2b(As[set][0].w); \
    u0[4] = f2b(As[set][1].x); u0[5] = f2b(As[set][1].y); \
    u0[6] = f2b(As[set][1].z); u0[7] = f2b(As[set][1].w); \
    u1[0] = f2b(As[set][2].x); u1[1] = f2b(As[set][2].y); \
    u1[2] = f2b(As[set][2].z); u1[3] = f2b(As[set][2].w); \
    u1[4] = f2b(As[set][3].x); u1[5] = f2b(As[set][3].y); \
    u1[6] = f2b(As[set][3].z); u1[7] = f2b(As[set][3].w); \
    unsigned short* Ad = Aring + (abuf) * 8192; \
    *(v8us*)(Ad + ar0 * 64 + acs * 8) = u0; \
    *(v8us*)(Ad + (ar0 + 64) * 64 + acs * 8) = u1; } while (0)

#define COMPUTE(bslot, abuf) do { \
    const unsigned short* Alc = Aring + (abuf) * 8192; \
    const unsigned short* Blc = Bring + (bslot) * 16384; \
    _Pragma("unroll") \
    for (int ks = 0; ks < 2; ++ks) { \
      const int kb = ks * 4; \
      v8bf av[4], bv[4]; \
      _Pragma("unroll") \
      for (int mi = 0; mi < 4; ++mi) { \
        int m = wm * 64 + mi * 16 + l16; \
        av[mi] = us2bf(*(const v8us*)(Alc + m * 64 + (((kb + quad) ^ (m & 7)) * 8))); \
      } \
      _Pragma("unroll") \
      for (int ni = 0; ni < 4; ++ni) { \
        int o = wn * 64 + ni * 16 + l16; \
        bv[ni] = us2bf(*(const v8us*)(Blc + o * 64 + (((kb + quad) ^ (o & 7)) * 8))); \
      } \
      _Pragma("unroll") \
      for (int mi = 0; mi < 4; ++mi) \
        _Pragma("unroll") \
        for (int ni = 0; ni < 4; ++ni) \
          acc[mi][ni] = __builtin_amdgcn_mfma_f32_16x16x32_bf16(av[mi], bv[ni], acc[mi][ni], 0, 0, 0); \
    } } while (0)

  // ---- prologue: FIFO = [B0(4), A0(4), B1(4), A1(4), A2(4)] = 20 outstanding
  ISSUE_B(0, c0 + 0); SCHED0();
  ISSUE_A(0, c0 + 0); SCHED0();
  ISSUE_B(1, c0 + 1); SCHED0();
  ISSUE_A(1, c0 + 1); SCHED0();
  ISSUE_A(2, c0 + 2); SCHED0();
  waitv12();                 // drains B0, A0; leaves [B1,A1,A2]=12 in flight
  SCHED0();
  CONV_A(0, 0);
  waitl0();

#pragma unroll
  for (int t = 0; t < CPS_; ++t) {
    __builtin_amdgcn_s_barrier();   // B[t] visible (all waves), A[t] visible
    SCHED0();
    if (t + 2 < CPS_) { ISSUE_B((t + 2) % 3, c0 + t + 2); }
    SCHED0();
    if (t + 3 < CPS_) { ISSUE_A((t + 3) % 3, c0 + t + 3); }
    SCHED0();
    COMPUTE(t % 3, t & 1);
    if (t + 1 < CPS_) {
      // drain exactly through B[t+1], A[t+1]; keep newer 12 (8/0 at tail)
      if (t < 17)       waitv12();
      else if (t == 17) waitv8();
      else              waitv0();
      SCHED0();
      CONV_A((t + 1) % 3, (t + 1) & 1);
    }
    waitl0();                       // ds_writes visible before next barrier
  }

#undef ISSUE_B
#undef ISSUE_A
#undef CONV_A
#undef COMPUTE

  // epilogue: plain coalesced stores to this split's private partial buffer
  float* pb = part + (((size_t)sp * B_ + b) * N_) * DOUT_;
#pragma unroll
  for (int mi = 0; mi < 4; ++mi)
#pragma unroll
    for (int t4 = 0; t4 < 4; ++t4) {
      int row = n0 + wm * 64 + mi * 16 + quad * 4 + t4;
#pragma unroll
      for (int ni = 0; ni < 4; ++ni) {
        int col = wn * 64 + ni * 16 + l16;
        pb[(size_t)row * DOUT_ + col] = acc[mi][ni][t4];
      }
    }
}

// ---------------- reduce: out = bias + sum_sp part[sp] -------------------------
__global__ void reduce_out(const float* __restrict__ part, const float* __restrict__ bias,
                           float* __restrict__ out) {
  const size_t idx = (size_t)blockIdx.x * 256 + threadIdx.x;  // float4 index
  const size_t stride = (size_t)B_ * N_ * DOUT_ / 4;          // 524288
  f32x4 a = *(const f32x4*)(bias + (idx & 63) * 4);
#pragma unroll
  for (int s = 0; s < SPLITS_; ++s) {
    f32x4 p = *(const f32x4*)((const float*)part + (stride * s + idx) * 4);
    a += p;
  }
  *(f32x4*)(out + idx * 4) = a;
}

// ---------------- launch -------------------------------------------------------
extern "C" void kernel_launch(void* const* d_in, const int* in_sizes, int n_in,
                              void* d_out, int out_size, void* d_ws, size_t ws_size,
                              hipStream_t stream) {
  const float* node = (const float*)d_in[0];
  const float* rel  = (const float*)d_in[1];
  const float* adj  = (const float*)d_in[2];
  const float* W    = (const float*)d_in[3];
  const float* bias = (const float*)d_in[4];
  float* out = (float*)d_out;

  char* ws = (char*)d_ws;
  // layout (~80 MB total):
  unsigned short* nodeB = (unsigned short*)(ws);                      // 4 MB
  unsigned short* WnB   = (unsigned short*)(ws + ((size_t)5 << 20));  // 1.25 MB
  float*          Uf    = (float*)         (ws + ((size_t)7 << 20));  // 160 KB
  unsigned short* Gp    = (unsigned short*)(ws + ((size_t)8 << 20));  // 40 MB
  float*          part  = (float*)         (ws + ((size_t)48 << 20)); // 32 MB (4 x 8MB)

  prep_all<<<dim3(1056), 256, 0, stream>>>(node, W, rel, nodeB, WnB, Uf);
  stageA_gemm<<<dim3(B_ * R_, DOUT_ / 128, N_ / 128), 256, 0, stream>>>(nodeB, WnB, Uf, Gp);
  stageB_gemm<<<dim3(B_, N_ / 128, SPLITS_), 512, 0, stream>>>(adj, Gp, part);
  reduce_out<<<dim3((B_ * N_ * DOUT_ / 4) / 256), 256, 0, stream>>>(part, bias, out);
}

// Round 4
// 291.180 us; speedup vs baseline: 1.0319x; 1.0319x over previous
//
#include <hip/hip_runtime.h>
#include <stdint.h>

// Problem constants
#define B_     16
#define N_     512
#define R_     10
#define DE_    256
#define DR_    64
#define DOUT_  256
#define INDIM_ 3200   // (DE+DR)*R
#define BLK_   320    // DE+DR
#define RN_    5120   // R*N, K-extent of stage B
#define SPLITS_ 4     // stage B split-K factor
#define CPS_    20    // BK=64 chunks per split (80 total / 4)

typedef __bf16          v8bf  __attribute__((ext_vector_type(8)));
typedef unsigned short  v8us  __attribute__((ext_vector_type(8)));
typedef unsigned short  v4us  __attribute__((ext_vector_type(4)));
typedef float           f32x4 __attribute__((ext_vector_type(4)));

static __device__ __forceinline__ unsigned short f2b(float f) {
  union { float f; unsigned u; } c; c.f = f;
  unsigned r = c.u + 0x7FFFu + ((c.u >> 16) & 1u);   // RNE
  return (unsigned short)(r >> 16);
}

static __device__ __forceinline__ v8bf us2bf(v8us u) {
  union { v8us u; v8bf b; } c; c.u = u; return c.b;
}

// async global->LDS, 16B per lane; LDS dest = wave-uniform base + lane*16
static __device__ __forceinline__ void gl_lds16(const void* g, void* l) {
  __builtin_amdgcn_global_load_lds(
      (const __attribute__((address_space(1))) void*)g,
      (__attribute__((address_space(3))) void*)l, 16, 0, 0);
}

static __device__ __forceinline__ void waitv4() { asm volatile("s_waitcnt vmcnt(4)" ::: "memory"); }
static __device__ __forceinline__ void waitv0() { asm volatile("s_waitcnt vmcnt(0)" ::: "memory"); }
static __device__ __forceinline__ void waitl0() { asm volatile("s_waitcnt lgkmcnt(0)" ::: "memory"); }
#define SCHED0() __builtin_amdgcn_sched_barrier(0)

// ---------------- merged prep: nodeB + WnB + Uf in one launch ------------------
__global__ void prep_all(const float* __restrict__ nf, const float* __restrict__ W,
                         const float* __restrict__ rel,
                         unsigned short* __restrict__ nodeB,
                         unsigned short* __restrict__ WnB,
                         float* __restrict__ Uf) {
  const int bb = blockIdx.x;
  const int tid = threadIdx.x;
  if (bb < 256) {
    const size_t base = (size_t)bb * 8192;
#pragma unroll
    for (int p = 0; p < 4; ++p) {
      size_t off = base + (size_t)p * 2048 + (size_t)tid * 8;
      float4 x = *(const float4*)(nf + off);
      float4 y = *(const float4*)(nf + off + 4);
      v8us u;
      u[0] = f2b(x.x); u[1] = f2b(x.y); u[2] = f2b(x.z); u[3] = f2b(x.w);
      u[4] = f2b(y.x); u[5] = f2b(y.y); u[6] = f2b(y.z); u[7] = f2b(y.w);
      *(v8us*)(nodeB + off) = u;
    }
  } else if (bb < 896) {
    int idx = (bb - 256) * 1024 + tid * 4;          // < 655360, 4-aligned
    int r = idx >> 16;
    int o = (idx >> 8) & 255;
    int d = idx & 255;                               // 4-aligned, stays in row
    float4 x = *(const float4*)(W + (size_t)o * INDIM_ + r * BLK_ + d);
    v4us u;
    u[0] = f2b(x.x); u[1] = f2b(x.y); u[2] = f2b(x.z); u[3] = f2b(x.w);
    *(v4us*)(WnB + idx) = u;
  } else {
    int idx = (bb - 896) * 256 + tid;                // < B*R*DOUT = 40960
    int o  = idx & 255;
    int br = idx >> 8;                                // b*R + r
    int r  = br % R_;
    const float* rp = rel + (size_t)br * DR_;
    const float* wp = W + (size_t)o * INDIM_ + r * BLK_ + DE_;
    float v = 0.f;
#pragma unroll 8
    for (int d = 0; d < DR_; ++d) v += rp[d] * wp[d];
    Uf[idx] = v;
  }
}

// ---------------- stage A (v1, the best-measured config): ----------------------
// G'[b][o][(r,m)] = Wn[r] @ nodeB[b]^T + U. Per (b,r): M=256, N=512, K=256.
// 128x128 tile, BK=64, 4 waves 2x2, 32 KB LDS -> 5 blocks/CU (TLP hides drains).
__global__ void stageA_gemm(const unsigned short* __restrict__ nodeB,
                            const unsigned short* __restrict__ WnB,
                            const float* __restrict__ Uf,
                            unsigned short* __restrict__ Gp) {
  __shared__ unsigned short S[128 * 128];   // 32 KB: staging (Al|Bl) then C-tile
  unsigned short* Al = S;                   // 128x64 Wn rows (o)
  unsigned short* Bl = S + 128 * 64;        // 128x64 node rows (m)
  const int br = blockIdx.x;                // b*R + r
  const int b  = br / R_, r = br % R_;
  const int o0 = blockIdx.y * 128;
  const int m0 = blockIdx.z * 128;
  const int tid  = threadIdx.x;
  const int lane = tid & 63;
  const int wave = tid >> 6;
  const int wm = wave >> 1, wn = wave & 1;
  const int quad = lane >> 4, l16 = lane & 15;

  const unsigned short* Wb = WnB + (size_t)r * (DOUT_ * DE_);
  const unsigned short* Nb = nodeB + (size_t)b * (N_ * DE_);

  f32x4 acc[4][4];
#pragma unroll
  for (int i = 0; i < 4; ++i)
#pragma unroll
    for (int j = 0; j < 4; ++j) acc[i][j] = f32x4{0.f, 0.f, 0.f, 0.f};

  for (int dk = 0; dk < DE_; dk += 64) {
#pragma unroll
    for (int it = 0; it < 4; ++it) {
      int rowblk = it * 32 + wave * 8;
      int rl = rowblk + (lane >> 3);
      int kc = (lane & 7) ^ (rl & 7);
      gl_lds16(Wb + (size_t)(o0 + rl) * DE_ + dk + kc * 8, Al + rowblk * 64);
      gl_lds16(Nb + (size_t)(m0 + rl) * DE_ + dk + kc * 8, Bl + rowblk * 64);
    }
    __syncthreads();
#pragma unroll
    for (int ks = 0; ks < 2; ++ks) {
      const int kb = ks * 4;
      v8bf av[4], bv[4];
#pragma unroll
      for (int mi = 0; mi < 4; ++mi) {
        int m = wm * 64 + mi * 16 + l16;
        av[mi] = us2bf(*(const v8us*)(Al + m * 64 + (((kb + quad) ^ (m & 7)) * 8)));
      }
#pragma unroll
      for (int ni = 0; ni < 4; ++ni) {
        int c = wn * 64 + ni * 16 + l16;
        bv[ni] = us2bf(*(const v8us*)(Bl + c * 64 + (((kb + quad) ^ (c & 7)) * 8)));
      }
#pragma unroll
      for (int mi = 0; mi < 4; ++mi)
#pragma unroll
        for (int ni = 0; ni < 4; ++ni)
          acc[mi][ni] = __builtin_amdgcn_mfma_f32_16x16x32_bf16(av[mi], bv[ni], acc[mi][ni], 0, 0, 0);
    }
    __syncthreads();
  }

  // epilogue: C tile -> LDS (bf16, +U), then coalesced 16B stores to G'
#pragma unroll
  for (int mi = 0; mi < 4; ++mi)
#pragma unroll
    for (int t = 0; t < 4; ++t) {
      int o_loc = wm * 64 + mi * 16 + quad * 4 + t;
      float u = Uf[(size_t)br * DOUT_ + o0 + o_loc];
#pragma unroll
      for (int ni = 0; ni < 4; ++ni) {
        int m_loc = wn * 64 + ni * 16 + l16;
        S[o_loc * 128 + m_loc] = f2b(acc[mi][ni][t] + u);
      }
    }
  __syncthreads();
#pragma unroll
  for (int p = 0; p < 8; ++p) {
    int idx16 = p * 2048 + tid * 8;         // u16 index into S
    int orow = idx16 >> 7;                  // 0..127
    int moff = idx16 & 127;
    unsigned short* dst = Gp + ((size_t)(b * DOUT_ + o0 + orow)) * RN_ + r * N_ + m0 + moff;
    *(v8us*)dst = *(const v8us*)(S + idx16);
  }
}

// ---------------- stage B v5: part[sp][b] = adj(fp32) @ G' slice ---------------
// v2's geometry (128n x 256o tile, BK=64, 8 waves 2x4, 96 KB double buffer,
// grid 16x4x4 = 256 blocks = 1/CU) + corrected counted-wait pipeline:
// per iter t: issue B[t+1] gl_lds, then A[t+2] reg-loads -> MFMA(t) ->
// s_waitcnt vmcnt(4) (drains A[t+1]+B[t+1]; A[t+2] stays in flight; never 0
// until tail) -> convert A[t+1]->LDS -> lgkmcnt(0) -> s_barrier.
// adj (HBM-cold) gets ~1.5 iters of latency budget; Gp (L3-warm, 4x reuse
// across n-tiles) gets one compute phase. Loop unrolled x2 for static
// buffer/reg-set parity only; minimal sched_barrier use.
__global__ __launch_bounds__(512, 1)
void stageB_gemm(const float* __restrict__ adj,
                 const unsigned short* __restrict__ Gp,
                 float* __restrict__ part) {
  // per buffer: A 128x64 (8192 u16, 16 KB) + B 256x64 (16384 u16, 32 KB)
  __shared__ unsigned short SB[2 * 24576];  // 96 KB
  const int b  = blockIdx.x;
  const int n0 = blockIdx.y * 128;
  const int sp = blockIdx.z;                // chunks [sp*20, sp*20+20)
  const int tid  = threadIdx.x;
  const int lane = tid & 63;
  const int wave = tid >> 6;
  const int wm = wave >> 2;                 // 0..1 : n 64-row half
  const int wn = wave & 3;                  // 0..3 : o 64-col quarter
  const int quad = lane >> 4, l16 = lane & 15;

  const float* Ab = adj + (size_t)b * (R_ * N_ * N_);
  const unsigned short* Gb = Gp + (size_t)b * (DOUT_ * RN_);

  f32x4 acc[4][4];
#pragma unroll
  for (int i = 0; i < 4; ++i)
#pragma unroll
    for (int j = 0; j < 4; ++j) acc[i][j] = f32x4{0.f, 0.f, 0.f, 0.f};

  // A staging: thread covers rows {ar0, ar0+64}, 8 floats each at col ac8*8
  const int ar0 = tid >> 3;                 // 0..63
  const int ac8 = tid & 7;
  const int acs = ac8 ^ (ar0 & 7);          // XOR slot ((ar0+64)&7 == ar0&7)
  // B staging: per issue-round s, wave covers rows [s*64+wave*8, +8)
  const int brl = wave * 8 + (lane >> 3);
  const int bkc = lane & 7;
  const int c0 = sp * CPS_;                 // first BK=64 chunk id

  float4 As0[4], As1[4];                    // two in-flight A register sets

#define ISSUE_B(slot, cc) do { \
    unsigned short* Bd = SB + (slot) * 24576 + 8192; \
    const int k0b = (cc) << 6; \
    _Pragma("unroll") \
    for (int s = 0; s < 4; ++s) { \
      int rl = s * 64 + brl; \
      int kc = bkc ^ (rl & 7); \
      gl_lds16(Gb + (size_t)rl * RN_ + k0b + kc * 8, Bd + (s * 64 + wave * 8) * 64); \
    } } while (0)

#define ISSUE_A(AR, cc) do { \
    const float* g = Ab + ((size_t)((cc) >> 3) * N_ + n0) * N_ + ((cc) & 7) * 64 \
                     + (size_t)ar0 * N_ + ac8 * 8; \
    AR[0] = *(const float4*)(g); \
    AR[1] = *(const float4*)(g + 4); \
    AR[2] = *(const float4*)(g + 64 * N_); \
    AR[3] = *(const float4*)(g + 64 * N_ + 4); } while (0)

#define CONV_A(AR, slot) do { \
    v8us u0, u1; \
    u0[0] = f2b(AR[0].x); u0[1] = f2b(AR[0].y); u0[2] = f2b(AR[0].z); u0[3] = f2b(AR[0].w); \
    u0[4] = f2b(AR[1].x); u0[5] = f2b(AR[1].y); u0[6] = f2b(AR[1].z); u0[7] = f2b(AR[1].w); \
    u1[0] = f2b(AR[2].x); u1[1] = f2b(AR[2].y); u1[2] = f2b(AR[2].z); u1[3] = f2b(AR[2].w); \
    u1[4] = f2b(AR[3].x); u1[5] = f2b(AR[3].y); u1[6] = f2b(AR[3].z); u1[7] = f2b(AR[3].w); \
    unsigned short* Ad = SB + (slot) * 24576; \
    *(v8us*)(Ad + ar0 * 64 + acs * 8) = u0; \
    *(v8us*)(Ad + (ar0 + 64) * 64 + acs * 8) = u1; } while (0)

#define COMPUTE(slot) do { \
    const unsigned short* Alc = SB + (slot) * 24576; \
    const unsigned short* Blc = Alc + 8192; \
    _Pragma("unroll") \
    for (int ks = 0; ks < 2; ++ks) { \
      const int kb = ks * 4; \
      v8bf av[4], bv[4]; \
      _Pragma("unroll") \
      for (int mi = 0; mi < 4; ++mi) { \
        int m = wm * 64 + mi * 16 + l16; \
        av[mi] = us2bf(*(const v8us*)(Alc + m * 64 + (((kb + quad) ^ (m & 7)) * 8))); \
      } \
      _Pragma("unroll") \
      for (int ni = 0; ni < 4; ++ni) { \
        int o = wn * 64 + ni * 16 + l16; \
        bv[ni] = us2bf(*(const v8us*)(Blc + o * 64 + (((kb + quad) ^ (o & 7)) * 8))); \
      } \
      _Pragma("unroll") \
      for (int mi = 0; mi < 4; ++mi) \
        _Pragma("unroll") \
        for (int ni = 0; ni < 4; ++ni) \
          acc[mi][ni] = __builtin_amdgcn_mfma_f32_16x16x32_bf16(av[mi], bv[ni], acc[mi][ni], 0, 0, 0); \
    } } while (0)

  // ---- prologue. FIFO after issues: [A0(4), B0(4), A1(4)] = 12
  ISSUE_A(As0, c0 + 0);
  ISSUE_B(0, c0 + 0);
  ISSUE_A(As1, c0 + 1);
  waitv4();                 // drains A0 + B0; leaves A1(4) in flight
  SCHED0();
  CONV_A(As0, 0);           // A0 -> LDS slot 0
  waitl0();
  __builtin_amdgcn_s_barrier();

  for (int t = 0; t < CPS_; t += 2) {
    // ---- even sub-iter t: compute slot0; stage B[t+1]->slot1, A[t+2]->As0;
    //      convert A[t+1] (As1) -> slot1.
    {
      ISSUE_B(1, c0 + t + 1);                 // t+1 <= 19 < CPS always
      if (t + 2 < CPS_) ISSUE_A(As0, c0 + t + 2);
      SCHED0();
      COMPUTE(0);
      if (t + 2 < CPS_) waitv4();             // drains A[t+1]+B[t+1]; A[t+2] flies
      else              waitv0();             // tail: nothing newer to keep
      SCHED0();
      CONV_A(As1, 1);                         // A[t+1] -> LDS slot 1
      waitl0();
      __builtin_amdgcn_s_barrier();
    }
    // ---- odd sub-iter t+1: compute slot1; stage B[t+2]->slot0, A[t+3]->As1;
    //      convert A[t+2] (As0) -> slot0.
    {
      if (t + 2 < CPS_) {
        ISSUE_B(0, c0 + t + 2);
        if (t + 3 < CPS_) ISSUE_A(As1, c0 + t + 3);
        SCHED0();
        COMPUTE(1);
        if (t + 3 < CPS_) waitv4();
        else              waitv0();
        SCHED0();
        CONV_A(As0, 0);                       // A[t+2] -> LDS slot 0
        waitl0();
        __builtin_amdgcn_s_barrier();
      } else {
        SCHED0();
        COMPUTE(1);                           // final chunk; nothing in flight
      }
    }
  }

#undef ISSUE_B
#undef ISSUE_A
#undef CONV_A
#undef COMPUTE

  // epilogue: plain coalesced stores to this split's private partial buffer
  float* pb = part + (((size_t)sp * B_ + b) * N_) * DOUT_;
#pragma unroll
  for (int mi = 0; mi < 4; ++mi)
#pragma unroll
    for (int t4 = 0; t4 < 4; ++t4) {
      int row = n0 + wm * 64 + mi * 16 + quad * 4 + t4;
#pragma unroll
      for (int ni = 0; ni < 4; ++ni) {
        int col = wn * 64 + ni * 16 + l16;
        pb[(size_t)row * DOUT_ + col] = acc[mi][ni][t4];
      }
    }
}

// ---------------- reduce: out = bias + sum_sp part[sp] -------------------------
__global__ void reduce_out(const float* __restrict__ part, const float* __restrict__ bias,
                           float* __restrict__ out) {
  const size_t idx = (size_t)blockIdx.x * 256 + threadIdx.x;  // float4 index
  const size_t stride = (size_t)B_ * N_ * DOUT_ / 4;          // 524288
  f32x4 a = *(const f32x4*)(bias + (idx & 63) * 4);
#pragma unroll
  for (int s = 0; s < SPLITS_; ++s) {
    f32x4 p = *(const f32x4*)((const float*)part + (stride * s + idx) * 4);
    a += p;
  }
  *(f32x4*)(out + idx * 4) = a;
}

// ---------------- launch -------------------------------------------------------
extern "C" void kernel_launch(void* const* d_in, const int* in_sizes, int n_in,
                              void* d_out, int out_size, void* d_ws, size_t ws_size,
                              hipStream_t stream) {
  const float* node = (const float*)d_in[0];
  const float* rel  = (const float*)d_in[1];
  const float* adj  = (const float*)d_in[2];
  const float* W    = (const float*)d_in[3];
  const float* bias = (const float*)d_in[4];
  float* out = (float*)d_out;

  char* ws = (char*)d_ws;
  // layout (~80 MB total):
  unsigned short* nodeB = (unsigned short*)(ws);                      // 4 MB
  unsigned short* WnB   = (unsigned short*)(ws + ((size_t)5 << 20));  // 1.25 MB
  float*          Uf    = (float*)         (ws + ((size_t)7 << 20));  // 160 KB
  unsigned short* Gp    = (unsigned short*)(ws + ((size_t)8 << 20));  // 40 MB
  float*          part  = (float*)         (ws + ((size_t)48 << 20)); // 32 MB (4 x 8MB)

  prep_all<<<dim3(1056), 256, 0, stream>>>(node, W, rel, nodeB, WnB, Uf);
  stageA_gemm<<<dim3(B_ * R_, DOUT_ / 128, N_ / 128), 256, 0, stream>>>(nodeB, WnB, Uf, Gp);
  stageB_gemm<<<dim3(B_, N_ / 128, SPLITS_), 512, 0, stream>>>(adj, Gp, part);
  reduce_out<<<dim3((B_ * N_ * DOUT_ / 4) / 256), 256, 0, stream>>>(part, bias, out);
}

// Round 7
// 289.516 us; speedup vs baseline: 1.0379x; 1.0057x over previous
//
#include <hip/hip_runtime.h>
#include <stdint.h>

// Problem constants
#define B_     16
#define N_     512
#define R_     10
#define DE_    256
#define DR_    64
#define DOUT_  256
#define INDIM_ 3200   // (DE+DR)*R
#define BLK_   320    // DE+DR
#define RN_    5120   // R*N, K-extent of stage B
#define SPLITS_ 4     // stage B split-K factor
#define CPS_    20    // BK=64 chunks per split (80 total / 4)

typedef __bf16          v8bf  __attribute__((ext_vector_type(8)));
typedef unsigned short  v8us  __attribute__((ext_vector_type(8)));
typedef unsigned short  v4us  __attribute__((ext_vector_type(4)));
typedef float           f32x4 __attribute__((ext_vector_type(4)));

static __device__ __forceinline__ unsigned short f2b(float f) {
  union { float f; unsigned u; } c; c.f = f;
  unsigned r = c.u + 0x7FFFu + ((c.u >> 16) & 1u);   // RNE
  return (unsigned short)(r >> 16);
}

static __device__ __forceinline__ v8bf us2bf(v8us u) {
  union { v8us u; v8bf b; } c; c.u = u; return c.b;
}

// async global->LDS, 16B per lane; LDS dest = wave-uniform base + lane*16
static __device__ __forceinline__ void gl_lds16(const void* g, void* l) {
  __builtin_amdgcn_global_load_lds(
      (const __attribute__((address_space(1))) void*)g,
      (__attribute__((address_space(3))) void*)l, 16, 0, 0);
}

static __device__ __forceinline__ void waitv4() { asm volatile("s_waitcnt vmcnt(4)" ::: "memory"); }
static __device__ __forceinline__ void waitv0() { asm volatile("s_waitcnt vmcnt(0)" ::: "memory"); }
static __device__ __forceinline__ void waitl0() { asm volatile("s_waitcnt lgkmcnt(0)" ::: "memory"); }
#define SCHED0() __builtin_amdgcn_sched_barrier(0)

// ---------------- merged prep: nodeB + WnB + Uf in one launch ------------------
__global__ void prep_all(const float* __restrict__ nf, const float* __restrict__ W,
                         const float* __restrict__ rel,
                         unsigned short* __restrict__ nodeB,
                         unsigned short* __restrict__ WnB,
                         float* __restrict__ Uf) {
  const int bb = blockIdx.x;
  const int tid = threadIdx.x;
  if (bb < 256) {
    const size_t base = (size_t)bb * 8192;
#pragma unroll
    for (int p = 0; p < 4; ++p) {
      size_t off = base + (size_t)p * 2048 + (size_t)tid * 8;
      float4 x = *(const float4*)(nf + off);
      float4 y = *(const float4*)(nf + off + 4);
      v8us u;
      u[0] = f2b(x.x); u[1] = f2b(x.y); u[2] = f2b(x.z); u[3] = f2b(x.w);
      u[4] = f2b(y.x); u[5] = f2b(y.y); u[6] = f2b(y.z); u[7] = f2b(y.w);
      *(v8us*)(nodeB + off) = u;
    }
  } else if (bb < 896) {
    int idx = (bb - 256) * 1024 + tid * 4;          // < 655360, 4-aligned
    int r = idx >> 16;
    int o = (idx >> 8) & 255;
    int d = idx & 255;                               // 4-aligned, stays in row
    float4 x = *(const float4*)(W + (size_t)o * INDIM_ + r * BLK_ + d);
    v4us u;
    u[0] = f2b(x.x); u[1] = f2b(x.y); u[2] = f2b(x.z); u[3] = f2b(x.w);
    *(v4us*)(WnB + idx) = u;
  } else {
    int idx = (bb - 896) * 256 + tid;                // < B*R*DOUT = 40960
    int o  = idx & 255;
    int br = idx >> 8;                                // b*R + r
    int r  = br % R_;
    const float* rp = rel + (size_t)br * DR_;
    const float* wp = W + (size_t)o * INDIM_ + r * BLK_ + DE_;
    float v = 0.f;
#pragma unroll 8
    for (int d = 0; d < DR_; ++d) v += rp[d] * wp[d];
    Uf[idx] = v;
  }
}

// ---------------- stage A v3: r-merged, node-resident --------------------------
// G'[b][o][(r,m)] = Wn[r] @ nodeB[b]^T + U. Block = (b, o-half 128, m-tile 64,
// r-half 5). Node tile (64m x 256k) staged ONCE as 4 resident 64x64 panels
// (proven layout+swizzle); then 5 r x 4 K-steps = 20 steps/block with
// double-buffered Wn chunk prefetch. Per-r epilogue: proven LDS transpose ->
// coalesced 16B stores. Grid 16x2x16 = 512 blocks = 2/CU (80 KB LDS each),
// 256 thr, 4 waves 2(o)x2(m). 5x longer block life amortizes startup/drains.
__global__ void stageA_gemm(const unsigned short* __restrict__ nodeB,
                            const unsigned short* __restrict__ WnB,
                            const float* __restrict__ Uf,
                            unsigned short* __restrict__ Gp) {
  __shared__ unsigned short S[40960];       // 80 KB
  unsigned short* NodeP = S;                // 4 panels x (64m x 64k)  (32 KB)
  unsigned short* Wbuf  = S + 16384;        // 2 bufs  x (128o x 64k)  (32 KB)
  unsigned short* Cb    = S + 32768;        // 128o x 64m              (16 KB)
  const int b  = blockIdx.x;
  const int o0 = blockIdx.y * 128;
  const int m0 = (blockIdx.z & 7) * 64;
  const int r0 = (blockIdx.z >> 3) * 5;
  const int tid  = threadIdx.x;
  const int lane = tid & 63;
  const int wave = tid >> 6;
  const int wm = wave >> 1, wn = wave & 1;
  const int quad = lane >> 4, l16 = lane & 15;
  const int srl = lane >> 3;                // staging row within 8-row group
  const int skc = lane & 7;                 // staging 16B chunk

  const unsigned short* Nb = nodeB + (size_t)b * (N_ * DE_);

  // ---- prologue: resident node panels (panel p = k in [64p, 64p+64))
#pragma unroll
  for (int p = 0; p < 4; ++p)
#pragma unroll
    for (int it = 0; it < 2; ++it) {
      int rowblk = it * 32 + wave * 8;
      int rl = rowblk + srl;
      int kc = skc ^ (rl & 7);
      gl_lds16(Nb + (size_t)(m0 + rl) * DE_ + p * 64 + kc * 8,
               NodeP + p * 4096 + rowblk * 64);
    }
  // ---- prologue: Wn chunk (r0, t=0) -> buf0
  {
    const unsigned short* Wb = WnB + (size_t)r0 * (DOUT_ * DE_);
#pragma unroll
    for (int it = 0; it < 4; ++it) {
      int rowblk = it * 32 + wave * 8;
      int rl = rowblk + srl;
      int kc = skc ^ (rl & 7);
      gl_lds16(Wb + (size_t)(o0 + rl) * DE_ + kc * 8, Wbuf + rowblk * 64);
    }
  }
  __syncthreads();

  for (int rr = 0; rr < 5; ++rr) {
    const int r = r0 + rr;
    f32x4 acc[4][2];
#pragma unroll
    for (int i = 0; i < 4; ++i)
#pragma unroll
      for (int j = 0; j < 2; ++j) acc[i][j] = f32x4{0.f, 0.f, 0.f, 0.f};

#pragma unroll
    for (int t = 0; t < 4; ++t) {
      // prefetch next Wn chunk into buf (t+1)&1 (parity of global chunk idx)
      if (rr < 4 || t < 3) {
        const int nr = (t < 3) ? r : (r + 1);
        const int nt = (t < 3) ? (t + 1) : 0;
        const unsigned short* Wb = WnB + (size_t)nr * (DOUT_ * DE_);
        unsigned short* Wd = Wbuf + ((t + 1) & 1) * 8192;
#pragma unroll
        for (int it = 0; it < 4; ++it) {
          int rowblk = it * 32 + wave * 8;
          int rl = rowblk + srl;
          int kc = skc ^ (rl & 7);
          gl_lds16(Wb + (size_t)(o0 + rl) * DE_ + nt * 64 + kc * 8, Wd + rowblk * 64);
        }
      }
      // compute chunk (r, t): A = Wbuf[t&1] (128o x 64k), B = NodeP[t] (64m x 64k)
      const unsigned short* Wc = Wbuf + (t & 1) * 8192;
      const unsigned short* Np = NodeP + t * 4096;
#pragma unroll
      for (int ks = 0; ks < 2; ++ks) {
        const int kb = ks * 4;
        v8bf av[4], bv[2];
#pragma unroll
        for (int mi = 0; mi < 4; ++mi) {
          int m = wm * 64 + mi * 16 + l16;
          av[mi] = us2bf(*(const v8us*)(Wc + m * 64 + (((kb + quad) ^ (m & 7)) * 8)));
        }
#pragma unroll
        for (int ni = 0; ni < 2; ++ni) {
          int c = wn * 32 + ni * 16 + l16;
          bv[ni] = us2bf(*(const v8us*)(Np + c * 64 + (((kb + quad) ^ (c & 7)) * 8)));
        }
#pragma unroll
        for (int mi = 0; mi < 4; ++mi)
#pragma unroll
          for (int ni = 0; ni < 2; ++ni)
            acc[mi][ni] = __builtin_amdgcn_mfma_f32_16x16x32_bf16(av[mi], bv[ni], acc[mi][ni], 0, 0, 0);
      }
      __syncthreads();   // drains prefetch vmcnt; next buffer ready
    }

    // ---- per-r epilogue: C -> LDS (bf16, +U), then coalesced 16B stores
#pragma unroll
    for (int mi = 0; mi < 4; ++mi)
#pragma unroll
      for (int tt = 0; tt < 4; ++tt) {
        int o_loc = wm * 64 + mi * 16 + quad * 4 + tt;
        float u = Uf[((size_t)b * R_ + r) * DOUT_ + o0 + o_loc];
#pragma unroll
        for (int ni = 0; ni < 2; ++ni) {
          int m_loc = wn * 32 + ni * 16 + l16;
          Cb[o_loc * 64 + m_loc] = f2b(acc[mi][ni][tt] + u);
        }
      }
    __syncthreads();
#pragma unroll
    for (int p = 0; p < 4; ++p) {
      int idx16 = p * 2048 + tid * 8;       // u16 index into Cb
      int orow = idx16 >> 6;                // 0..127
      int moff = idx16 & 63;
      unsigned short* dst = Gp + ((size_t)(b * DOUT_ + o0 + orow)) * RN_ + r * N_ + m0 + moff;
      *(v8us*)dst = *(const v8us*)(Cb + idx16);
    }
    __syncthreads();   // Cb free before next r's writes
  }
}

// ---------------- stage B v5 (R4-passing, byte-identical) ----------------------
// 128n x 256o tile, BK=64, 8 waves 2x4, 96 KB double buffer, grid 16x4x4 =
// 256 blocks (1/CU). Counted-wait pipeline: per iter t issue B[t+1] gl_lds +
// A[t+2] reg-loads -> MFMA(t) -> vmcnt(4) -> convert A[t+1]->LDS -> lgkm(0)
// -> barrier.
__global__ __launch_bounds__(512, 1)
void stageB_gemm(const float* __restrict__ adj,
                 const unsigned short* __restrict__ Gp,
                 float* __restrict__ part) {
  // per buffer: A 128x64 (8192 u16, 16 KB) + B 256x64 (16384 u16, 32 KB)
  __shared__ unsigned short SB[2 * 24576];  // 96 KB
  const int b  = blockIdx.x;
  const int n0 = blockIdx.y * 128;
  const int sp = blockIdx.z;                // chunks [sp*20, sp*20+20)
  const int tid  = threadIdx.x;
  const int lane = tid & 63;
  const int wave = tid >> 6;
  const int wm = wave >> 2;                 // 0..1 : n 64-row half
  const int wn = wave & 3;                  // 0..3 : o 64-col quarter
  const int quad = lane >> 4, l16 = lane & 15;

  const float* Ab = adj + (size_t)b * (R_ * N_ * N_);
  const unsigned short* Gb = Gp + (size_t)b * (DOUT_ * RN_);

  f32x4 acc[4][4];
#pragma unroll
  for (int i = 0; i < 4; ++i)
#pragma unroll
    for (int j = 0; j < 4; ++j) acc[i][j] = f32x4{0.f, 0.f, 0.f, 0.f};

  // A staging: thread covers rows {ar0, ar0+64}, 8 floats each at col ac8*8
  const int ar0 = tid >> 3;                 // 0..63
  const int ac8 = tid & 7;
  const int acs = ac8 ^ (ar0 & 7);          // XOR slot ((ar0+64)&7 == ar0&7)
  // B staging: per issue-round s, wave covers rows [s*64+wave*8, +8)
  const int brl = wave * 8 + (lane >> 3);
  const int bkc = lane & 7;
  const int c0 = sp * CPS_;                 // first BK=64 chunk id

  float4 As0[4], As1[4];                    // two in-flight A register sets

#define ISSUE_B(slot, cc) do { \
    unsigned short* Bd = SB + (slot) * 24576 + 8192; \
    const int k0b = (cc) << 6; \
    _Pragma("unroll") \
    for (int s = 0; s < 4; ++s) { \
      int rl = s * 64 + brl; \
      int kc = bkc ^ (rl & 7); \
      gl_lds16(Gb + (size_t)rl * RN_ + k0b + kc * 8, Bd + (s * 64 + wave * 8) * 64); \
    } } while (0)

#define ISSUE_A(AR, cc) do { \
    const float* g = Ab + ((size_t)((cc) >> 3) * N_ + n0) * N_ + ((cc) & 7) * 64 \
                     + (size_t)ar0 * N_ + ac8 * 8; \
    AR[0] = *(const float4*)(g); \
    AR[1] = *(const float4*)(g + 4); \
    AR[2] = *(const float4*)(g + 64 * N_); \
    AR[3] = *(const float4*)(g + 64 * N_ + 4); } while (0)

#define CONV_A(AR, slot) do { \
    v8us u0, u1; \
    u0[0] = f2b(AR[0].x); u0[1] = f2b(AR[0].y); u0[2] = f2b(AR[0].z); u0[3] = f2b(AR[0].w); \
    u0[4] = f2b(AR[1].x); u0[5] = f2b(AR[1].y); u0[6] = f2b(AR[1].z); u0[7] = f2b(AR[1].w); \
    u1[0] = f2b(AR[2].x); u1[1] = f2b(AR[2].y); u1[2] = f2b(AR[2].z); u1[3] = f2b(AR[2].w); \
    u1[4] = f2b(AR[3].x); u1[5] = f2b(AR[3].y); u1[6] = f2b(AR[3].z); u1[7] = f2b(AR[3].w); \
    unsigned short* Ad = SB + (slot) * 24576; \
    *(v8us*)(Ad + ar0 * 64 + acs * 8) = u0; \
    *(v8us*)(Ad + (ar0 + 64) * 64 + acs * 8) = u1; } while (0)

#define COMPUTE(slot) do { \
    const unsigned short* Alc = SB + (slot) * 24576; \
    const unsigned short* Blc = Alc + 8192; \
    _Pragma("unroll") \
    for (int ks = 0; ks < 2; ++ks) { \
      const int kb = ks * 4; \
      v8bf av[4], bv[4]; \
      _Pragma("unroll") \
      for (int mi = 0; mi < 4; ++mi) { \
        int m = wm * 64 + mi * 16 + l16; \
        av[mi] = us2bf(*(const v8us*)(Alc + m * 64 + (((kb + quad) ^ (m & 7)) * 8))); \
      } \
      _Pragma("unroll") \
      for (int ni = 0; ni < 4; ++ni) { \
        int o = wn * 64 + ni * 16 + l16; \
        bv[ni] = us2bf(*(const v8us*)(Blc + o * 64 + (((kb + quad) ^ (o & 7)) * 8))); \
      } \
      _Pragma("unroll") \
      for (int mi = 0; mi < 4; ++mi) \
        _Pragma("unroll") \
        for (int ni = 0; ni < 4; ++ni) \
          acc[mi][ni] = __builtin_amdgcn_mfma_f32_16x16x32_bf16(av[mi], bv[ni], acc[mi][ni], 0, 0, 0); \
    } } while (0)

  // ---- prologue. FIFO after issues: [A0(4), B0(4), A1(4)] = 12
  ISSUE_A(As0, c0 + 0);
  ISSUE_B(0, c0 + 0);
  ISSUE_A(As1, c0 + 1);
  waitv4();                 // drains A0 + B0; leaves A1(4) in flight
  SCHED0();
  CONV_A(As0, 0);           // A0 -> LDS slot 0
  waitl0();
  __builtin_amdgcn_s_barrier();

  for (int t = 0; t < CPS_; t += 2) {
    // ---- even sub-iter t
    {
      ISSUE_B(1, c0 + t + 1);
      if (t + 2 < CPS_) ISSUE_A(As0, c0 + t + 2);
      SCHED0();
      COMPUTE(0);
      if (t + 2 < CPS_) waitv4();
      else              waitv0();
      SCHED0();
      CONV_A(As1, 1);
      waitl0();
      __builtin_amdgcn_s_barrier();
    }
    // ---- odd sub-iter t+1
    {
      if (t + 2 < CPS_) {
        ISSUE_B(0, c0 + t + 2);
        if (t + 3 < CPS_) ISSUE_A(As1, c0 + t + 3);
        SCHED0();
        COMPUTE(1);
        if (t + 3 < CPS_) waitv4();
        else              waitv0();
        SCHED0();
        CONV_A(As0, 0);
        waitl0();
        __builtin_amdgcn_s_barrier();
      } else {
        SCHED0();
        COMPUTE(1);
      }
    }
  }

#undef ISSUE_B
#undef ISSUE_A
#undef CONV_A
#undef COMPUTE

  // epilogue: plain coalesced stores to this split's private partial buffer
  float* pb = part + (((size_t)sp * B_ + b) * N_) * DOUT_;
#pragma unroll
  for (int mi = 0; mi < 4; ++mi)
#pragma unroll
    for (int t4 = 0; t4 < 4; ++t4) {
      int row = n0 + wm * 64 + mi * 16 + quad * 4 + t4;
#pragma unroll
      for (int ni = 0; ni < 4; ++ni) {
        int col = wn * 64 + ni * 16 + l16;
        pb[(size_t)row * DOUT_ + col] = acc[mi][ni][t4];
      }
    }
}

// ---------------- reduce: out = bias + sum_sp part[sp] -------------------------
__global__ void reduce_out(const float* __restrict__ part, const float* __restrict__ bias,
                           float* __restrict__ out) {
  const size_t idx = (size_t)blockIdx.x * 256 + threadIdx.x;  // float4 index
  const size_t stride = (size_t)B_ * N_ * DOUT_ / 4;          // 524288
  f32x4 a = *(const f32x4*)(bias + (idx & 63) * 4);
#pragma unroll
  for (int s = 0; s < SPLITS_; ++s) {
    f32x4 p = *(const f32x4*)((const float*)part + (stride * s + idx) * 4);
    a += p;
  }
  *(f32x4*)(out + idx * 4) = a;
}

// ---------------- launch -------------------------------------------------------
extern "C" void kernel_launch(void* const* d_in, const int* in_sizes, int n_in,
                              void* d_out, int out_size, void* d_ws, size_t ws_size,
                              hipStream_t stream) {
  const float* node = (const float*)d_in[0];
  const float* rel  = (const float*)d_in[1];
  const float* adj  = (const float*)d_in[2];
  const float* W    = (const float*)d_in[3];
  const float* bias = (const float*)d_in[4];
  float* out = (float*)d_out;

  char* ws = (char*)d_ws;
  // layout (80 MB total, proven envelope):
  unsigned short* nodeB = (unsigned short*)(ws);                      // 4 MB
  unsigned short* WnB   = (unsigned short*)(ws + ((size_t)5 << 20));  // 1.25 MB
  float*          Uf    = (float*)         (ws + ((size_t)7 << 20));  // 160 KB
  unsigned short* Gp    = (unsigned short*)(ws + ((size_t)8 << 20));  // 40 MB
  float*          part  = (float*)         (ws + ((size_t)48 << 20)); // 32 MB (4 x 8MB)

  prep_all<<<dim3(1056), 256, 0, stream>>>(node, W, rel, nodeB, WnB, Uf);
  stageA_gemm<<<dim3(B_, 2, 16), 256, 0, stream>>>(nodeB, WnB, Uf, Gp);
  stageB_gemm<<<dim3(B_, N_ / 128, SPLITS_), 512, 0, stream>>>(adj, Gp, part);
  reduce_out<<<dim3((B_ * N_ * DOUT_ / 4) / 256), 256, 0, stream>>>(part, bias, out);
}